// Round 4
// baseline (295.734 us; speedup 1.0000x reference)
//
#include <hip/hip_runtime.h>
#include <math.h>

#define N_NODES 20000
#define N_EDGES 640000

// ---------------------------------------------------------------------------
// Kernel A: xr1 = x @ w_rel1   ;   h1 = x @ w_root1 + b_rel1
// x: [N,128], weights [128,64]. One wave computes 4 nodes (lane = out feature).
// Weights staged in LDS (2 x 32KB). LDS reads are 2-lanes/bank (free).
// ---------------------------------------------------------------------------
__global__ __launch_bounds__(256) void gcn_l1(
    const float* __restrict__ x,
    const float* __restrict__ w_rel, const float* __restrict__ b_rel,
    const float* __restrict__ w_root,
    float* __restrict__ xr1, float* __restrict__ h1)
{
    __shared__ float s_wr[128 * 64];
    __shared__ float s_wo[128 * 64];
    for (int i = threadIdx.x; i < 128 * 64; i += 256) {
        s_wr[i] = w_rel[i];
        s_wo[i] = w_root[i];
    }
    __syncthreads();

    const int wave = threadIdx.x >> 6;
    const int lane = threadIdx.x & 63;
    const float brl = b_rel[lane];

    // 4 nodes per wave per iteration; block covers 16 nodes.
    for (int n0 = blockIdx.x * 16 + wave * 4; n0 < N_NODES; n0 += gridDim.x * 16) {
        const float4* xr0 = (const float4*)(x + (n0 + 0) * 128);
        const float4* xr1p = (const float4*)(x + (n0 + 1) * 128);
        const float4* xr2 = (const float4*)(x + (n0 + 2) * 128);
        const float4* xr3 = (const float4*)(x + (n0 + 3) * 128);
        float ar0 = 0.f, ao0 = 0.f, ar1 = 0.f, ao1 = 0.f;
        float ar2 = 0.f, ao2 = 0.f, ar3 = 0.f, ao3 = 0.f;
        #pragma unroll 8
        for (int k4 = 0; k4 < 32; ++k4) {
            float4 a = xr0[k4], b = xr1p[k4], c = xr2[k4], d = xr3[k4];
            const int kb = k4 * 4;
            {
                float wr = s_wr[(kb + 0) * 64 + lane], wo = s_wo[(kb + 0) * 64 + lane];
                ar0 += a.x * wr; ao0 += a.x * wo; ar1 += b.x * wr; ao1 += b.x * wo;
                ar2 += c.x * wr; ao2 += c.x * wo; ar3 += d.x * wr; ao3 += d.x * wo;
            }
            {
                float wr = s_wr[(kb + 1) * 64 + lane], wo = s_wo[(kb + 1) * 64 + lane];
                ar0 += a.y * wr; ao0 += a.y * wo; ar1 += b.y * wr; ao1 += b.y * wo;
                ar2 += c.y * wr; ao2 += c.y * wo; ar3 += d.y * wr; ao3 += d.y * wo;
            }
            {
                float wr = s_wr[(kb + 2) * 64 + lane], wo = s_wo[(kb + 2) * 64 + lane];
                ar0 += a.z * wr; ao2 += c.z * wo; ar1 += b.z * wr; ao1 += b.z * wo;
                ar2 += c.z * wr; ao0 += a.z * wo; ar3 += d.z * wr; ao3 += d.z * wo;
            }
            {
                float wr = s_wr[(kb + 3) * 64 + lane], wo = s_wo[(kb + 3) * 64 + lane];
                ar0 += a.w * wr; ao0 += a.w * wo; ar1 += b.w * wr; ao1 += b.w * wo;
                ar2 += c.w * wr; ao2 += c.w * wo; ar3 += d.w * wr; ao3 += d.w * wo;
            }
        }
        xr1[(n0 + 0) * 64 + lane] = ar0;
        xr1[(n0 + 1) * 64 + lane] = ar1;
        xr1[(n0 + 2) * 64 + lane] = ar2;
        xr1[(n0 + 3) * 64 + lane] = ar3;
        h1[(n0 + 0) * 64 + lane] = ao0 + brl;
        h1[(n0 + 1) * 64 + lane] = ao1 + brl;
        h1[(n0 + 2) * 64 + lane] = ao2 + brl;
        h1[(n0 + 3) * 64 + lane] = ao3 + brl;
    }
}

// ---------------------------------------------------------------------------
// Kernel B: h1[dst] += xr1[src]  (64 features; one wave per edge, lane=feature)
// ---------------------------------------------------------------------------
__global__ __launch_bounds__(256) void scatter1(
    const int* __restrict__ ei, const float* __restrict__ xr1,
    float* __restrict__ h1)
{
    const int lane = threadIdx.x & 63;
    const int wid = (blockIdx.x * 256 + threadIdx.x) >> 6;
    const int nw = (gridDim.x * 256) >> 6;
    for (int e = wid; e < N_EDGES; e += nw) {
        const int s = ei[e];
        const int d = ei[N_EDGES + e];
        const float v = xr1[s * 64 + lane];
        unsafeAtomicAdd(&h1[d * 64 + lane], v);
    }
}

// ---------------------------------------------------------------------------
// Kernel C: h2 = relu(h1 @ w_l1 + b_l1)  [N,32]
//           hr2 = h2 @ w_rel2            [N,16]
//           g2  = h2 @ w_root2 + b_rel2  [N,16]
// One thread per node; all weights in LDS (uniform-broadcast reads).
// ---------------------------------------------------------------------------
__global__ __launch_bounds__(256) void mlp_l2pre(
    const float* __restrict__ h1,
    const float* __restrict__ w_l1, const float* __restrict__ b_l1,
    const float* __restrict__ w_rel2, const float* __restrict__ b_rel2,
    const float* __restrict__ w_root2,
    float* __restrict__ hr2, float* __restrict__ g2)
{
    __shared__ float s_wl1[64 * 32];
    __shared__ float s_wr2[32 * 16];
    __shared__ float s_wo2[32 * 16];
    __shared__ float s_bl1[32];
    __shared__ float s_br2[16];
    for (int i = threadIdx.x; i < 64 * 32; i += 256) s_wl1[i] = w_l1[i];
    for (int i = threadIdx.x; i < 32 * 16; i += 256) {
        s_wr2[i] = w_rel2[i];
        s_wo2[i] = w_root2[i];
    }
    if (threadIdx.x < 32) s_bl1[threadIdx.x] = b_l1[threadIdx.x];
    if (threadIdx.x < 16) s_br2[threadIdx.x] = b_rel2[threadIdx.x];
    __syncthreads();

    const int n = blockIdx.x * 256 + threadIdx.x;
    if (n >= N_NODES) return;

    float h2[32];
    #pragma unroll
    for (int j = 0; j < 32; ++j) h2[j] = s_bl1[j];

    const float4* h1v = (const float4*)(h1 + n * 64);
    #pragma unroll 4
    for (int k4 = 0; k4 < 16; ++k4) {
        const float4 xv = h1v[k4];
        const float xs[4] = {xv.x, xv.y, xv.z, xv.w};
        #pragma unroll
        for (int kk = 0; kk < 4; ++kk) {
            const float xv1 = xs[kk];
            const float4* wrow = (const float4*)(s_wl1 + (k4 * 4 + kk) * 32);
            #pragma unroll
            for (int j4 = 0; j4 < 8; ++j4) {
                const float4 w = wrow[j4];
                h2[j4 * 4 + 0] += xv1 * w.x;
                h2[j4 * 4 + 1] += xv1 * w.y;
                h2[j4 * 4 + 2] += xv1 * w.z;
                h2[j4 * 4 + 3] += xv1 * w.w;
            }
        }
    }
    #pragma unroll
    for (int j = 0; j < 32; ++j) h2[j] = fmaxf(h2[j], 0.f);

    float o_r[16], o_g[16];
    #pragma unroll
    for (int j = 0; j < 16; ++j) { o_r[j] = 0.f; o_g[j] = s_br2[j]; }
    #pragma unroll 8
    for (int k = 0; k < 32; ++k) {
        const float hv = h2[k];
        const float4* wr = (const float4*)(s_wr2 + k * 16);
        const float4* wo = (const float4*)(s_wo2 + k * 16);
        #pragma unroll
        for (int j4 = 0; j4 < 4; ++j4) {
            const float4 a = wr[j4], b = wo[j4];
            o_r[j4 * 4 + 0] += hv * a.x; o_g[j4 * 4 + 0] += hv * b.x;
            o_r[j4 * 4 + 1] += hv * a.y; o_g[j4 * 4 + 1] += hv * b.y;
            o_r[j4 * 4 + 2] += hv * a.z; o_g[j4 * 4 + 2] += hv * b.z;
            o_r[j4 * 4 + 3] += hv * a.w; o_g[j4 * 4 + 3] += hv * b.w;
        }
    }
    float4* hr2v = (float4*)(hr2 + n * 16);
    float4* g2v = (float4*)(g2 + n * 16);
    #pragma unroll
    for (int j4 = 0; j4 < 4; ++j4) {
        hr2v[j4] = make_float4(o_r[j4 * 4 + 0], o_r[j4 * 4 + 1], o_r[j4 * 4 + 2], o_r[j4 * 4 + 3]);
        g2v[j4] = make_float4(o_g[j4 * 4 + 0], o_g[j4 * 4 + 1], o_g[j4 * 4 + 2], o_g[j4 * 4 + 3]);
    }
}

// ---------------------------------------------------------------------------
// Kernel D: g2[dst] += hr2[src]   (16 features; thread = (edge, feature))
// ---------------------------------------------------------------------------
__global__ __launch_bounds__(256) void scatter2(
    const int* __restrict__ ei, const float* __restrict__ hr2,
    float* __restrict__ g2)
{
    const int stride = gridDim.x * 256;
    for (int i = blockIdx.x * 256 + threadIdx.x; i < N_EDGES * 16; i += stride) {
        const int e = i >> 4;
        const int f = i & 15;
        const int s = ei[e];
        const int d = ei[N_EDGES + e];
        unsafeAtomicAdd(&g2[d * 16 + f], hr2[s * 16 + f]);
    }
}

// ---------------------------------------------------------------------------
// Kernel E: logits = g2 @ w_l2 + b_l2 ; out = log_softmax(logits)
// ---------------------------------------------------------------------------
__global__ __launch_bounds__(256) void head(
    const float* __restrict__ g2,
    const float* __restrict__ w_l2, const float* __restrict__ b_l2,
    float* __restrict__ out)
{
    __shared__ float s_w[16 * 10];
    __shared__ float s_b[10];
    for (int i = threadIdx.x; i < 160; i += 256) s_w[i] = w_l2[i];
    if (threadIdx.x < 10) s_b[threadIdx.x] = b_l2[threadIdx.x];
    __syncthreads();

    const int n = blockIdx.x * 256 + threadIdx.x;
    if (n >= N_NODES) return;

    float g[16];
    const float4* gv = (const float4*)(g2 + n * 16);
    #pragma unroll
    for (int i = 0; i < 4; ++i) {
        const float4 v = gv[i];
        g[i * 4 + 0] = v.x; g[i * 4 + 1] = v.y; g[i * 4 + 2] = v.z; g[i * 4 + 3] = v.w;
    }
    float l[10];
    #pragma unroll
    for (int j = 0; j < 10; ++j) l[j] = s_b[j];
    #pragma unroll
    for (int k = 0; k < 16; ++k) {
        const float hv = g[k];
        #pragma unroll
        for (int j = 0; j < 10; ++j) l[j] += hv * s_w[k * 10 + j];
    }
    float m = l[0];
    #pragma unroll
    for (int j = 1; j < 10; ++j) m = fmaxf(m, l[j]);
    float ssum = 0.f;
    #pragma unroll
    for (int j = 0; j < 10; ++j) ssum += expf(l[j] - m);
    const float lse = m + logf(ssum);
    #pragma unroll
    for (int j = 0; j < 10; ++j) out[n * 10 + j] = l[j] - lse;
}

// ---------------------------------------------------------------------------
extern "C" void kernel_launch(void* const* d_in, const int* in_sizes, int n_in,
                              void* d_out, int out_size, void* d_ws, size_t ws_size,
                              hipStream_t stream) {
    const float* x       = (const float*)d_in[0];
    const int*   ei      = (const int*)d_in[1];
    const float* w_rel1  = (const float*)d_in[2];
    const float* b_rel1  = (const float*)d_in[3];
    const float* w_root1 = (const float*)d_in[4];
    const float* w_l1    = (const float*)d_in[5];
    const float* b_l1    = (const float*)d_in[6];
    const float* w_rel2  = (const float*)d_in[7];
    const float* b_rel2  = (const float*)d_in[8];
    const float* w_root2 = (const float*)d_in[9];
    const float* w_l2    = (const float*)d_in[10];
    const float* b_l2    = (const float*)d_in[11];
    float* out = (float*)d_out;

    float* ws  = (float*)d_ws;
    float* xr1 = ws;                 // [20000,64]
    float* h1  = ws + 1280000;       // [20000,64]
    float* hr2 = ws + 2560000;       // [20000,16]
    float* g2  = ws + 2880000;       // [20000,16]

    gcn_l1<<<1250, 256, 0, stream>>>(x, w_rel1, b_rel1, w_root1, xr1, h1);
    scatter1<<<4096, 256, 0, stream>>>(ei, xr1, h1);
    mlp_l2pre<<<(N_NODES + 255) / 256, 256, 0, stream>>>(
        h1, w_l1, b_l1, w_rel2, b_rel2, w_root2, hr2, g2);
    scatter2<<<4096, 256, 0, stream>>>(ei, hr2, g2);
    head<<<(N_NODES + 255) / 256, 256, 0, stream>>>(g2, w_l2, b_l2, out);
}